// Round 7
// baseline (509.765 us; speedup 1.0000x reference)
//
#include <hip/hip_runtime.h>

#define NPTS 32768
#define PREC 1057           // partial record: 1024 S + 32 m + 1 nk
#define ELDSF 19520         // estep LDS floats: 17408 A2t + 1024 DG + 1024 b2 + 32 cvec + 32 coef

// ---------------- shared inverse + pack (LDS M = [cov | I], 256 threads) ----------------
// A packed upper-triangle pairs: row d has (33-d)>>1 pairs (e0=d+2j, e1=e0+1; A=0 pad at e1==32).
// A2t[t*64 + k*2 + {0,1}]; DG[i*64 + k*2 + {0,1}] = A[2i][2i], A[2i+1][2i+1];
// b2[(d>>1)*64 + k*2 + (d&1)] = (A*mu)[d].
__device__ __forceinline__ void invert_pack(float M[32][66], const float* mu, float wk,
    int k, int tid, float* A2t, float* DG, float* b2, float* cvec, float* coef, float* bb)
{
    int r  = tid >> 3;
    int c0 = (tid & 7) * 8;
    float det = 1.0f;
    for (int s = 0; s < 32; ++s) {
        float piv = M[s][s];
        det *= piv;
        float rpv = 1.0f / piv;
        float f   = (r != s) ? M[r][s] : 0.0f;
        __syncthreads();
        if (tid < 64) M[s][tid] *= rpv;
        __syncthreads();
        if (r != s) {
            #pragma unroll
            for (int j = 0; j < 8; ++j) M[r][c0 + j] -= f * M[s][c0 + j];
        }
        __syncthreads();
    }
    // pack upper-triangle pairs
    for (int t = tid; t < 272; t += 256) {
        int d = 0, b = 0;
        while (t >= b + ((33 - d) >> 1)) { b += (33 - d) >> 1; ++d; }
        int j  = t - b;
        int e0 = d + 2 * j, e1 = e0 + 1;
        A2t[t * 64 + k * 2 + 0] = M[d][32 + e0];
        A2t[t * 64 + k * 2 + 1] = (e1 < 32) ? M[d][32 + e1] : 0.0f;
    }
    if (tid < 16) {
        DG[tid * 64 + k * 2 + 0] = M[2 * tid][32 + 2 * tid];
        DG[tid * 64 + k * 2 + 1] = M[2 * tid + 1][32 + 2 * tid + 1];
    }
    if (tid < 32) {
        float bd = 0.0f;
        #pragma unroll
        for (int e = 0; e < 32; ++e) bd += M[tid][32 + e] * mu[e];
        bb[tid] = bd;
        b2[(tid >> 1) * 64 + k * 2 + (tid & 1)] = bd;
    }
    __syncthreads();
    if (tid == 0) {
        float cc = 0.0f;
        #pragma unroll
        for (int d = 0; d < 32; ++d) cc += mu[d] * bb[d];
        cvec[k] = cc;
        coef[k] = wk / sqrtf(det);
    }
}

// ---------------- prep0: inverse from input cov/means/weights ----------------
__global__ __launch_bounds__(256) void prep0_kernel(
    const float* __restrict__ cov0, const float* __restrict__ means0,
    const float* __restrict__ w0,
    float* __restrict__ A2t, float* __restrict__ DG, float* __restrict__ b2,
    float* __restrict__ cvec, float* __restrict__ coef)
{
    int k = blockIdx.x, tid = threadIdx.x;
    __shared__ float M[32][66];
    __shared__ float MU[32], BB[32];
    for (int i = tid; i < 1024; i += 256) {
        int r = i >> 5, c = i & 31;
        M[r][c]      = cov0[k * 1024 + i];
        M[r][32 + c] = (r == c) ? 1.0f : 0.0f;
    }
    if (tid < 32) MU[tid] = means0[k * 32 + tid];
    __syncthreads();
    invert_pack(M, MU, w0[k], k, tid, A2t, DG, b2, cvec, coef, BB);
}

// ---------------- estep: responsibilities P[n][k] (triangle-packed A) ----------------
// block = 512 thr (8 waves); thread = (k = lane&31, 2 points). 32 pts/block, 1024 blocks.
__global__ __launch_bounds__(512, 4) void estep_kernel(
    const float* __restrict__ data, const float* __restrict__ A2g,
    float* __restrict__ P)
{
    __shared__ alignas(16) float A2s[ELDSF];   // 76.25 KiB
    int tid = threadIdx.x;
    for (int i = tid; i < ELDSF / 4; i += 512)
        ((float4*)A2s)[i] = ((const float4*)A2g)[i];
    __syncthreads();

    int lane = tid & 63;
    int wv   = tid >> 6;        // 0..7
    int k    = lane & 31;
    int g    = lane >> 5;
    int p0   = blockIdx.x * 32 + wv * 4 + g * 2;

    float x0[32], x1[32];
    {
        const float4* dp0 = (const float4*)(data + (size_t)p0 * 32);
        const float4* dp1 = (const float4*)(data + (size_t)(p0 + 1) * 32);
        #pragma unroll
        for (int j = 0; j < 8; ++j) {
            float4 v = dp0[j]; x0[4*j]=v.x; x0[4*j+1]=v.y; x0[4*j+2]=v.z; x0[4*j+3]=v.w;
            float4 u = dp1[j]; x1[4*j]=u.x; x1[4*j+1]=u.y; x1[4*j+2]=u.z; x1[4*j+3]=u.w;
        }
    }

    float q0 = 0.0f, q1 = 0.0f;
    int t = 0;
    #pragma unroll
    for (int d = 0; d < 32; ++d) {
        const int np = (33 - d) >> 1;
        float w0 = 0.0f, w1 = 0.0f;
        #pragma unroll
        for (int j = 0; j < np; ++j) {
            const int e0 = d + 2 * j;
            const int e1 = (e0 + 1 < 32) ? e0 + 1 : 31;   // pad pair has A=0
            float2 a = *(const float2*)&A2s[(t + j) * 64 + (k << 1)];
            w0 = __builtin_fmaf(a.y, x0[e1], __builtin_fmaf(a.x, x0[e0], w0));
            w1 = __builtin_fmaf(a.y, x1[e1], __builtin_fmaf(a.x, x1[e0], w1));
        }
        t += np;
        q0 += x0[d] * w0;
        q1 += x1[d] * w1;
    }
    float d20 = 0.0f, d21 = 0.0f;
    #pragma unroll
    for (int i = 0; i < 16; ++i) {
        float2 a = *(const float2*)&A2s[17408 + i * 64 + (k << 1)];
        float ta = a.x * x0[2*i];     d20 = __builtin_fmaf(ta, x0[2*i],   d20);
        float tb = a.y * x0[2*i+1];   d20 = __builtin_fmaf(tb, x0[2*i+1], d20);
        float tc = a.x * x1[2*i];     d21 = __builtin_fmaf(tc, x1[2*i],   d21);
        float td = a.y * x1[2*i+1];   d21 = __builtin_fmaf(td, x1[2*i+1], d21);
    }
    float bx0 = 0.0f, bx1 = 0.0f;
    #pragma unroll
    for (int i = 0; i < 16; ++i) {
        float2 b = *(const float2*)&A2s[18432 + i * 64 + (k << 1)];
        bx0 += b.x * x0[2*i] + b.y * x0[2*i+1];
        bx1 += b.x * x1[2*i] + b.y * x1[2*i+1];
    }
    float cc = A2s[19456 + k], cf = A2s[19488 + k];
    float e0v = cf * __expf(-0.5f * ((2.0f * q0 - d20) - 2.0f * bx0 + cc));
    float e1v = cf * __expf(-0.5f * ((2.0f * q1 - d21) - 2.0f * bx1 + cc));

    float t0 = e0v, t1 = e1v;
    #pragma unroll
    for (int m = 16; m >= 1; m >>= 1) {
        t0 += __shfl_xor(t0, m, 64);
        t1 += __shfl_xor(t1, m, 64);
    }
    P[(size_t)p0 * 32 + k]       = e0v / t0;
    P[(size_t)(p0 + 1) * 32 + k] = e1v / t1;
}

// ---------------- mstep: partial S, m, Nk per (k, chunk); p staged in LDS ----------------
// grid 1024; bid -> k = bid>>5, chunk = (bid&7)*4 + ((bid>>3)&3)  (XCD-local chunks)
__global__ __launch_bounds__(256, 4) void mstep_kernel(
    const float* __restrict__ data, const float* __restrict__ P,
    float* __restrict__ partial)
{
    int bid   = blockIdx.x;
    int k     = bid >> 5;
    int chunk = (bid & 7) * 4 + ((bid >> 3) & 3);
    int tid   = threadIdx.x;
    int tile  = tid & 31;
    int ng    = tid >> 5;
    int dt    = tile >> 2;   // d0 = 4*dt
    int et    = tile & 3;    // e0 = 8*et

    __shared__ alignas(16) float SH[9216];   // 36 KB: X(8192)+p(256) / combine 8*1088
    float* ps = SH + 8192;

    float acc[4][8];
    #pragma unroll
    for (int i = 0; i < 4; ++i)
        #pragma unroll
        for (int j = 0; j < 8; ++j) acc[i][j] = 0.0f;
    float m0=0, m1=0, m2=0, m3=0, nk=0;

    int base = chunk * 1024;
    for (int stage = 0; stage < 4; ++stage) {
        __syncthreads();
        for (int i = tid; i < 2048; i += 256)
            ((float4*)SH)[i] = ((const float4*)(data + (size_t)(base + stage * 256) * 32))[i];
        ps[tid] = P[(size_t)(base + stage * 256 + tid) * 32 + k];
        __syncthreads();
        const float4* X4 = (const float4*)SH;
        int nb = ng * 32;
        #pragma unroll 4
        for (int nn = 0; nn < 32; ++nn) {
            int n   = nb + nn;
            float p = ps[n];
            float4 xd  = X4[n * 8 + dt];
            float4 xe0 = X4[n * 8 + et * 2];
            float4 xe1 = X4[n * 8 + et * 2 + 1];
            float p0 = p * xd.x, p1 = p * xd.y, p2 = p * xd.z, p3 = p * xd.w;
            acc[0][0]+=p0*xe0.x; acc[0][1]+=p0*xe0.y; acc[0][2]+=p0*xe0.z; acc[0][3]+=p0*xe0.w;
            acc[0][4]+=p0*xe1.x; acc[0][5]+=p0*xe1.y; acc[0][6]+=p0*xe1.z; acc[0][7]+=p0*xe1.w;
            acc[1][0]+=p1*xe0.x; acc[1][1]+=p1*xe0.y; acc[1][2]+=p1*xe0.z; acc[1][3]+=p1*xe0.w;
            acc[1][4]+=p1*xe1.x; acc[1][5]+=p1*xe1.y; acc[1][6]+=p1*xe1.z; acc[1][7]+=p1*xe1.w;
            acc[2][0]+=p2*xe0.x; acc[2][1]+=p2*xe0.y; acc[2][2]+=p2*xe0.z; acc[2][3]+=p2*xe0.w;
            acc[2][4]+=p2*xe1.x; acc[2][5]+=p2*xe1.y; acc[2][6]+=p2*xe1.z; acc[2][7]+=p2*xe1.w;
            acc[3][0]+=p3*xe0.x; acc[3][1]+=p3*xe0.y; acc[3][2]+=p3*xe0.z; acc[3][3]+=p3*xe0.w;
            acc[3][4]+=p3*xe1.x; acc[3][5]+=p3*xe1.y; acc[3][6]+=p3*xe1.z; acc[3][7]+=p3*xe1.w;
            if (et == 0) { m0 += p0; m1 += p1; m2 += p2; m3 += p3; }
            if (tile == 0) nk += p;
        }
    }
    __syncthreads();   // X/p regions dead; reuse SH as combine scratch

    {
        float* Sg = SH + ng * 1088;
        #pragma unroll
        for (int i = 0; i < 4; ++i) {
            int row = dt * 4 + i;
            #pragma unroll
            for (int j = 0; j < 8; ++j) {
                int col = (et * 8 + j + dt) & 31;   // bank-rotated
                Sg[row * 32 + col] = acc[i][j];
            }
        }
        if (et == 0) {
            Sg[1024 + dt * 4 + 0] = m0; Sg[1024 + dt * 4 + 1] = m1;
            Sg[1024 + dt * 4 + 2] = m2; Sg[1024 + dt * 4 + 3] = m3;
        }
        if (tile == 0) Sg[1056] = nk;
    }
    __syncthreads();

    float* out = partial + (size_t)(chunk * 32 + k) * PREC;
    for (int e = tid; e < PREC; e += 256) {
        int ridx;
        if (e < 1024) {
            int row = e >> 5, col = e & 31;
            ridx = row * 32 + ((col + (row >> 2)) & 31);
        } else ridx = e;
        float s = 0.0f;
        #pragma unroll
        for (int gg = 0; gg < 8; ++gg) s += SH[gg * 1088 + ridx];
        out[e] = s;
    }
}

// ---------------- finprep: reduce partials; outputs; fused inverse for next iter ----------------
__global__ __launch_bounds__(256) void finprep_kernel(
    const float* __restrict__ partial, const float* __restrict__ means_old, int do_prep,
    float* __restrict__ A2t, float* __restrict__ DG, float* __restrict__ b2,
    float* __restrict__ cvec, float* __restrict__ coef,
    float* __restrict__ means_new, float* __restrict__ out)
{
    int k = blockIdx.x, tid = threadIdx.x;
    __shared__ float SS[PREC];
    __shared__ float MU[32], MB[32], BB[32];
    __shared__ float M[32][66];

    for (int e = tid; e < PREC; e += 256) {
        float s = 0.0f;
        for (int ch = 0; ch < 32; ++ch)
            s += partial[(size_t)(ch * 32 + k) * PREC + e];
        SS[e] = s;
    }
    if (tid < 32) MU[tid] = means_old[k * 32 + tid];
    __syncthreads();

    float nk  = SS[1056];
    float rnk = 1.0f / nk;
    float wk  = nk * (1.0f / (float)NPTS);
    if (tid < 32) {
        float mb = SS[1024 + tid] * rnk;
        MB[tid] = mb;
        means_new[k * 32 + tid] = mb;
        out[k * 32 + tid] = mb;
    }
    if (tid == 0) out[33792 + k] = wk;
    __syncthreads();

    for (int idx = tid; idx < 1024; idx += 256) {
        int d = idx >> 5, e = idx & 31;
        float c = SS[idx] * rnk - MU[d] * MB[e] - MB[d] * MU[e] + MU[d] * MU[e];
        out[1024 + k * 1024 + idx] = c;
        M[d][e]      = c;
        M[d][32 + e] = (d == e) ? 1.0f : 0.0f;
    }
    __syncthreads();

    if (do_prep) {
        invert_pack(M, MB, wk, k, tid, A2t, DG, b2, cvec, coef, BB);
    }
}

extern "C" void kernel_launch(void* const* d_in, const int* in_sizes, int n_in,
                              void* d_out, int out_size, void* d_ws, size_t ws_size,
                              hipStream_t stream) {
    (void)in_sizes; (void)n_in; (void)out_size; (void)ws_size;
    const float* data   = (const float*)d_in[0];
    const float* means0 = (const float*)d_in[1];
    const float* cov0   = (const float*)d_in[2];
    const float* w0     = (const float*)d_in[3];

    float* ws      = (float*)d_ws;
    float* A2t     = ws + 0;        // 17408   (A2t..coef contiguous = estep stage block)
    float* DG      = ws + 17408;    // 1024
    float* b2      = ws + 18432;    // 1024
    float* cvec    = ws + 19456;    // 32
    float* coef    = ws + 19488;    // 32
    float* meansA  = ws + 19520;    // 1024
    float* meansB  = ws + 20544;    // 1024
    float* P       = ws + 21568;    // 1048576
    float* partial = ws + 1070144;  // 32*32*1057 = 1082368 (end ~8.6 MB)

    prep0_kernel<<<32, 256, 0, stream>>>(cov0, means0, w0, A2t, DG, b2, cvec, coef);
    const float* mold = means0;
    for (int it = 0; it < 4; ++it) {
        float* mnew = (it & 1) ? meansB : meansA;
        estep_kernel<<<1024, 512, 0, stream>>>(data, ws, P);
        mstep_kernel<<<1024, 256, 0, stream>>>(data, P, partial);
        finprep_kernel<<<32, 256, 0, stream>>>(partial, mold, (it < 3) ? 1 : 0,
                                               A2t, DG, b2, cvec, coef, mnew, (float*)d_out);
        mold = mnew;
    }
}